// Round 1
// baseline (465.989 us; speedup 1.0000x reference)
//
#include <hip/hip_runtime.h>
#include <cstdint>
#include <cstddef>

// Problem constants (from reference file)
#define N_NODES 50000
#define N_EDGES 800000
#define D 128
#define M_ROWS (2 * N_NODES)   // B*N rows for the GEMM phase
#define LN_EPS 1e-5f

// ---------------------------------------------------------------------------
// CSR build: histogram -> exclusive scan -> scatter
// ---------------------------------------------------------------------------

__global__ __launch_bounds__(256) void k_hist(const int* __restrict__ rows,
                                              int* __restrict__ counts) {
  int e = blockIdx.x * 256 + threadIdx.x;
  if (e < N_EDGES) atomicAdd(&counts[rows[e]], 1);
}

__global__ __launch_bounds__(1024) void k_scan1(const int* __restrict__ counts,
                                                int* __restrict__ offs,
                                                int* __restrict__ bsum) {
  __shared__ int s[1024];
  int tid = threadIdx.x;
  int i = blockIdx.x * 1024 + tid;
  int v = (i < N_NODES) ? counts[i] : 0;
  s[tid] = v;
  __syncthreads();
  // Hillis-Steele inclusive scan
  for (int off = 1; off < 1024; off <<= 1) {
    int t = (tid >= off) ? s[tid - off] : 0;
    __syncthreads();
    s[tid] += t;
    __syncthreads();
  }
  if (i < N_NODES) offs[i] = s[tid] - v;        // exclusive
  if (tid == 1023) bsum[blockIdx.x] = s[tid];   // block total
}

__global__ void k_scan2(int* __restrict__ bsum, int nb) {
  if (threadIdx.x == 0) {
    int run = 0;
    for (int b = 0; b < nb; b++) { int t = bsum[b]; bsum[b] = run; run += t; }
  }
}

__global__ __launch_bounds__(1024) void k_scan3(int* __restrict__ offs,
                                                const int* __restrict__ bsum) {
  int i = blockIdx.x * 1024 + threadIdx.x;
  if (i < N_NODES) offs[i] += bsum[blockIdx.x];
}

__global__ __launch_bounds__(256) void k_scatter(const int* __restrict__ rows,
                                                 const int* __restrict__ cols,
                                                 const float* __restrict__ vals,
                                                 const int* __restrict__ offs,
                                                 int* __restrict__ cursor,
                                                 int* __restrict__ ccol,
                                                 float* __restrict__ cval) {
  int e = blockIdx.x * 256 + threadIdx.x;
  if (e < N_EDGES) {
    int r = rows[e];
    int pos = offs[r] + atomicAdd(&cursor[r], 1);
    ccol[pos] = cols[e];
    cval[pos] = vals[e];
  }
}

// ---------------------------------------------------------------------------
// Pull-style SpMM: one wave per row, 256 outputs (B*D) = 4 floats/lane.
// y layout: [B][N][D] flattened as m = b*N + n  ->  y[m*128 + d]
// ---------------------------------------------------------------------------
__global__ __launch_bounds__(256) void k_spmm(const float* __restrict__ x,
                                              const int* __restrict__ offs,
                                              const int* __restrict__ ccol,
                                              const float* __restrict__ cval,
                                              float* __restrict__ y) {
  int r = blockIdx.x * 4 + (threadIdx.x >> 6);
  int l = threadIdx.x & 63;
  int start = offs[r];
  int end = (r == N_NODES - 1) ? N_EDGES : offs[r + 1];
  float2 a0 = {0.f, 0.f}, a1 = {0.f, 0.f};
  const float* x1 = x + (size_t)N_NODES * D;   // batch 1 plane
  for (int k = start; k < end; k++) {
    int c = ccol[k];          // wave-uniform -> scalarized
    float v = cval[k];        // wave-uniform -> scalarized
    size_t base = (size_t)c * D + 2 * l;
    float2 v0 = *(const float2*)&x[base];      // 512B coalesced across wave
    float2 v1 = *(const float2*)&x1[base];
    a0.x += v * v0.x; a0.y += v * v0.y;
    a1.x += v * v1.x; a1.y += v * v1.y;
  }
  *(float2*)&y[(size_t)r * D + 2 * l] = a0;
  *(float2*)&y[((size_t)N_NODES + r) * D + 2 * l] = a1;
}

// ---------------------------------------------------------------------------
// Fused GEMM (fp32 vector) + bias + LayerNorm + exact GELU.
// h[m, j] = sum_d y[m, d] * W[d, j] + b[j]; per-wave: 8 rows, lane l owns
// columns {l, l+64}. W staged transposed+padded in LDS (wT[j][d], stride 132
// floats keeps 16B alignment and spreads banks).
// ---------------------------------------------------------------------------
__device__ inline float gelu_exact(float v) {
  return 0.5f * v * (1.0f + erff(v * 0.70710678118654752440f));
}

__global__ __launch_bounds__(256) void k_gemm_ln_gelu(const float* __restrict__ y,
                                                      const float* __restrict__ W,
                                                      const float* __restrict__ bias,
                                                      const float* __restrict__ gamma,
                                                      const float* __restrict__ beta,
                                                      float* __restrict__ out) {
  __shared__ float wT[128 * 132];   // 67,584 B (gfx950 allows up to 160 KB)
  int tid = threadIdx.x;
  for (int idx = tid; idx < 128 * 128; idx += 256) {
    int d = idx >> 7;
    int j = idx & 127;
    wT[j * 132 + d] = W[idx];       // global read coalesced over j
  }
  __syncthreads();

  int l = tid & 63;
  int wave = tid >> 6;
  int row0 = (blockIdx.x * 4 + wave) * 8;

  float b0 = bias[l],  b1 = bias[l + 64];
  float g0 = gamma[l], g1 = gamma[l + 64];
  float be0 = beta[l], be1 = beta[l + 64];

  float acc0[8], acc1[8];
#pragma unroll
  for (int r = 0; r < 8; r++) { acc0[r] = 0.f; acc1[r] = 0.f; }

  const float* yb = y + (size_t)row0 * D;
  for (int d4 = 0; d4 < 128; d4 += 4) {
    float4 wa = *(const float4*)&wT[l * 132 + d4];
    float4 wb = *(const float4*)&wT[(l + 64) * 132 + d4];
#pragma unroll
    for (int r = 0; r < 8; r++) {
      float4 yv = *(const float4*)&yb[r * D + d4];   // wave-uniform -> s_load
      acc0[r] += yv.x * wa.x + yv.y * wa.y + yv.z * wa.z + yv.w * wa.w;
      acc1[r] += yv.x * wb.x + yv.y * wb.y + yv.z * wb.z + yv.w * wb.w;
    }
  }

#pragma unroll
  for (int r = 0; r < 8; r++) {
    float h0 = acc0[r] + b0;
    float h1 = acc1[r] + b1;
    float s  = h0 + h1;
    float ss = h0 * h0 + h1 * h1;
#pragma unroll
    for (int off = 32; off >= 1; off >>= 1) {
      s  += __shfl_xor(s, off, 64);
      ss += __shfl_xor(ss, off, 64);
    }
    float mu  = s * (1.0f / 128.0f);
    float var = ss * (1.0f / 128.0f) - mu * mu;
    float inv = rsqrtf(var + LN_EPS);
    float o0 = (h0 - mu) * inv * g0 + be0;
    float o1 = (h1 - mu) * inv * g1 + be1;
    size_t m = (size_t)(row0 + r);
    out[m * D + l]      = gelu_exact(o0);
    out[m * D + l + 64] = gelu_exact(o1);
  }
}

// ---------------------------------------------------------------------------
// kernel_launch
// ---------------------------------------------------------------------------
extern "C" void kernel_launch(void* const* d_in, const int* in_sizes, int n_in,
                              void* d_out, int out_size, void* d_ws, size_t ws_size,
                              hipStream_t stream) {
  const float* x      = (const float*)d_in[0];
  const int*   A_rows = (const int*)d_in[1];
  const int*   A_cols = (const int*)d_in[2];
  const float* A_vals = (const float*)d_in[3];
  const float* W      = (const float*)d_in[4];
  const float* b      = (const float*)d_in[5];
  const float* gamma  = (const float*)d_in[6];
  const float* beta   = (const float*)d_in[7];
  float* out = (float*)d_out;

  // Workspace layout (~58 MB total)
  char* ws = (char*)d_ws;
  size_t off = 0;
  float* y = (float*)(ws + off);
  off += (((size_t)M_ROWS * D * sizeof(float)) + 255) & ~(size_t)255;   // 51.2 MB
  int* offs = (int*)(ws + off);
  off += (((size_t)N_NODES * sizeof(int)) + 255) & ~(size_t)255;
  int* counts = (int*)(ws + off);   // also reused as scatter cursor
  off += (((size_t)N_NODES * sizeof(int)) + 255) & ~(size_t)255;
  int* bsum = (int*)(ws + off);
  off += 4096;
  int* ccol = (int*)(ws + off);
  off += (size_t)N_EDGES * sizeof(int);
  float* cval = (float*)(ws + off);
  off += (size_t)N_EDGES * sizeof(float);

  const int nb = (N_NODES + 1023) / 1024;   // 49 scan blocks

  // 1. CSR build
  hipMemsetAsync(counts, 0, N_NODES * sizeof(int), stream);
  k_hist<<<(N_EDGES + 255) / 256, 256, 0, stream>>>(A_rows, counts);
  k_scan1<<<nb, 1024, 0, stream>>>(counts, offs, bsum);
  k_scan2<<<1, 64, 0, stream>>>(bsum, nb);
  k_scan3<<<nb, 1024, 0, stream>>>(offs, bsum);
  hipMemsetAsync(counts, 0, N_NODES * sizeof(int), stream);   // reuse as cursor
  k_scatter<<<(N_EDGES + 255) / 256, 256, 0, stream>>>(A_rows, A_cols, A_vals,
                                                       offs, counts, ccol, cval);

  // 2. Pull SpMM (no float atomics)
  k_spmm<<<N_NODES / 4, 256, 0, stream>>>(x, offs, ccol, cval, y);

  // 3. Fused Linear + LayerNorm + GELU
  k_gemm_ln_gelu<<<M_ROWS / 32, 256, 0, stream>>>(y, W, b, gamma, beta, out);
}

// Round 2
// 335.000 us; speedup vs baseline: 1.3910x; 1.3910x over previous
//
#include <hip/hip_runtime.h>
#include <cstdint>
#include <cstddef>

#define N_NODES 50000
#define N_EDGES 800000
#define D 128
#define M_ROWS (2 * N_NODES)     // B*N rows
#define N_TILES (M_ROWS / 16)    // 6250 row-tiles for MFMA GEMM
#define LN_EPS 1e-5f

typedef __attribute__((ext_vector_type(8))) short bf16x8;
typedef __attribute__((ext_vector_type(4))) float f32x4;

__device__ inline unsigned short bf16_rne(float f) {
  unsigned u = __float_as_uint(f);
  unsigned r = (u + 0x7FFFu + ((u >> 16) & 1u)) >> 16;
  return (unsigned short)r;
}

// ---------------------------------------------------------------------------
// Split W into transposed bf16 hi/lo planes: wt[j][k=d]  (W is [d][j])
// ---------------------------------------------------------------------------
__global__ __launch_bounds__(256) void k_splitw(const float* __restrict__ W,
                                                unsigned short* __restrict__ wt_hi,
                                                unsigned short* __restrict__ wt_lo) {
  int i = blockIdx.x * 256 + threadIdx.x;   // 16384 elements
  int d = i >> 7, j = i & 127;
  float v = W[i];
  unsigned short hb = bf16_rne(v);
  float rem = v - __uint_as_float((unsigned)hb << 16);
  wt_hi[j * 128 + d] = hb;
  wt_lo[j * 128 + d] = bf16_rne(rem);
}

// ---------------------------------------------------------------------------
// CSR build: histogram (into offs) -> in-place scan -> scatter (atomic cursor
// on offs itself; afterwards offs[r] = end offset of row r)
// ---------------------------------------------------------------------------
__global__ __launch_bounds__(256) void k_hist(const int* __restrict__ rows,
                                              int* __restrict__ offs) {
  int e = blockIdx.x * 256 + threadIdx.x;
  if (e < N_EDGES) atomicAdd(&offs[rows[e]], 1);
}

__global__ __launch_bounds__(1024) void k_scan1(int* __restrict__ offs,
                                                int* __restrict__ bsum) {
  __shared__ int s[1024];
  int tid = threadIdx.x;
  int i = blockIdx.x * 1024 + tid;
  int v = (i < N_NODES) ? offs[i] : 0;
  s[tid] = v;
  __syncthreads();
  for (int off = 1; off < 1024; off <<= 1) {
    int t = (tid >= off) ? s[tid - off] : 0;
    __syncthreads();
    s[tid] += t;
    __syncthreads();
  }
  if (i < N_NODES) offs[i] = s[tid] - v;        // exclusive
  if (tid == 1023) bsum[blockIdx.x] = s[tid];
}

__global__ void k_scan2(int* __restrict__ bsum, int nb) {
  if (threadIdx.x == 0) {
    int run = 0;
    for (int b = 0; b < nb; b++) { int t = bsum[b]; bsum[b] = run; run += t; }
  }
}

__global__ __launch_bounds__(1024) void k_scan3(int* __restrict__ offs,
                                                const int* __restrict__ bsum) {
  int i = blockIdx.x * 1024 + threadIdx.x;
  if (i < N_NODES) offs[i] += bsum[blockIdx.x];
}

__global__ __launch_bounds__(256) void k_scatter(const int* __restrict__ rows,
                                                 const int* __restrict__ cols,
                                                 const float* __restrict__ vals,
                                                 int* __restrict__ offs,
                                                 int2* __restrict__ epair) {
  int e = blockIdx.x * 256 + threadIdx.x;
  if (e < N_EDGES) {
    int r = rows[e];
    int pos = atomicAdd(&offs[r], 1);
    int2 p; p.x = cols[e]; p.y = __float_as_int(vals[e]);
    epair[pos] = p;
  }
}

// ---------------------------------------------------------------------------
// z = x @ W via split-bf16 MFMA (3 terms). One wave per 16-row tile, all 128
// cols. W (hi+lo, transposed) staged in 64KB LDS with XOR-16B swizzle so the
// j-strided ds_read_b128 is conflict-free.
// ---------------------------------------------------------------------------
__global__ __launch_bounds__(512) void k_gemm_z(const float* __restrict__ x,
                                                const unsigned short* __restrict__ wt_hi,
                                                const unsigned short* __restrict__ wt_lo,
                                                float* __restrict__ z) {
  __shared__ unsigned short lwhi[128 * 128];   // 32 KB
  __shared__ unsigned short lwlo[128 * 128];   // 32 KB
  int tid = threadIdx.x;

  // Stage W hi/lo into LDS (swizzled). 2048 16B-chunks per array.
  for (int c = tid; c < 2048; c += 512) {
    int j = c >> 4;
    int k16 = c & 15;
    int soff = j * 256 + ((k16 * 16) ^ ((j & 7) << 4));
    *reinterpret_cast<float4*>(reinterpret_cast<char*>(lwhi) + soff) =
        *reinterpret_cast<const float4*>(wt_hi + j * 128 + k16 * 8);
    *reinterpret_cast<float4*>(reinterpret_cast<char*>(lwlo) + soff) =
        *reinterpret_cast<const float4*>(wt_lo + j * 128 + k16 * 8);
  }

  int wave = tid >> 6, l = tid & 63;
  int tile = blockIdx.x * 8 + wave;
  bool active = tile < N_TILES;
  int lrow = l & 15;
  int kg = l >> 4;                  // 0..3  (k-group of the MFMA fragment)

  // Issue x loads before the barrier so they overlap W staging.
  float4 xv[4][2];
  if (active) {
    const float* xr = x + (size_t)(tile * 16 + lrow) * D + kg * 8;
#pragma unroll
    for (int kc = 0; kc < 4; kc++) {
      xv[kc][0] = *reinterpret_cast<const float4*>(xr + kc * 32);
      xv[kc][1] = *reinterpret_cast<const float4*>(xr + kc * 32 + 4);
    }
  }
  __syncthreads();
  if (!active) return;

  // Split A into hi/lo bf16 fragments.
  bf16x8 ahi[4], alo[4];
#pragma unroll
  for (int kc = 0; kc < 4; kc++) {
    float tmp[8];
    *reinterpret_cast<float4*>(&tmp[0]) = xv[kc][0];
    *reinterpret_cast<float4*>(&tmp[4]) = xv[kc][1];
    bf16x8 h, lo8;
#pragma unroll
    for (int e = 0; e < 8; e++) {
      unsigned short hb = bf16_rne(tmp[e]);
      float rem = tmp[e] - __uint_as_float((unsigned)hb << 16);
      h[e] = (short)hb;
      lo8[e] = (short)bf16_rne(rem);
    }
    ahi[kc] = h; alo[kc] = lo8;
  }

  f32x4 acc[8];
#pragma unroll
  for (int jt = 0; jt < 8; jt++) acc[jt] = (f32x4){0.f, 0.f, 0.f, 0.f};

#pragma unroll
  for (int kc = 0; kc < 4; kc++) {
#pragma unroll
    for (int jt = 0; jt < 8; jt++) {
      int j = jt * 16 + lrow;
      int kbyte = kc * 64 + kg * 16;
      int soff = j * 256 + (kbyte ^ ((j & 7) << 4));
      bf16x8 bhi = *reinterpret_cast<bf16x8*>(reinterpret_cast<char*>(lwhi) + soff);
      bf16x8 blo = *reinterpret_cast<bf16x8*>(reinterpret_cast<char*>(lwlo) + soff);
      acc[jt] = __builtin_amdgcn_mfma_f32_16x16x32_bf16(ahi[kc], bhi, acc[jt], 0, 0, 0);
      acc[jt] = __builtin_amdgcn_mfma_f32_16x16x32_bf16(alo[kc], bhi, acc[jt], 0, 0, 0);
      acc[jt] = __builtin_amdgcn_mfma_f32_16x16x32_bf16(ahi[kc], blo, acc[jt], 0, 0, 0);
    }
  }

  // C/D layout: col = lane&15 (within tile), row = (lane>>4)*4 + reg.
  int rb = tile * 16 + kg * 4;
#pragma unroll
  for (int r = 0; r < 4; r++) {
    float* zr = z + (size_t)(rb + r) * D + lrow;
#pragma unroll
    for (int jt = 0; jt < 8; jt++) zr[jt * 16] = acc[jt][r];
  }
}

// ---------------------------------------------------------------------------
// Pull SpMM over z, fused bias + LayerNorm + exact GELU. One wave per node,
// both batch planes (lane l owns cols 2l, 2l+1 of each plane).
// offs[] holds END offsets post-scatter; start = offs[r-1].
// ---------------------------------------------------------------------------
__device__ inline float gelu_exact(float v) {
  return 0.5f * v * (1.0f + erff(v * 0.70710678118654752440f));
}

__global__ __launch_bounds__(256) void k_spmm_ln(const float* __restrict__ z,
                                                 const int* __restrict__ offs,
                                                 const int2* __restrict__ epair,
                                                 const float* __restrict__ bias,
                                                 const float* __restrict__ gamma,
                                                 const float* __restrict__ beta,
                                                 float* __restrict__ out) {
  int r = blockIdx.x * 4 + (threadIdx.x >> 6);
  int l = threadIdx.x & 63;
  int start = (r == 0) ? 0 : offs[r - 1];
  int end = offs[r];

  float2 a0 = {0.f, 0.f}, a1 = {0.f, 0.f};
  const float* z1 = z + (size_t)N_NODES * D;

  int k = start;
  for (; k + 1 < end; k += 2) {
    int2 e0 = epair[k];
    int2 e1 = epair[k + 1];
    size_t b0 = (size_t)e0.x * D + 2 * l;
    size_t b1 = (size_t)e1.x * D + 2 * l;
    float v0 = __int_as_float(e0.y);
    float v1 = __int_as_float(e1.y);
    float2 p00 = *reinterpret_cast<const float2*>(&z[b0]);
    float2 p01 = *reinterpret_cast<const float2*>(&z1[b0]);
    float2 p10 = *reinterpret_cast<const float2*>(&z[b1]);
    float2 p11 = *reinterpret_cast<const float2*>(&z1[b1]);
    a0.x += v0 * p00.x; a0.y += v0 * p00.y;
    a1.x += v0 * p01.x; a1.y += v0 * p01.y;
    a0.x += v1 * p10.x; a0.y += v1 * p10.y;
    a1.x += v1 * p11.x; a1.y += v1 * p11.y;
  }
  if (k < end) {
    int2 e0 = epair[k];
    size_t b0 = (size_t)e0.x * D + 2 * l;
    float v0 = __int_as_float(e0.y);
    float2 p00 = *reinterpret_cast<const float2*>(&z[b0]);
    float2 p01 = *reinterpret_cast<const float2*>(&z1[b0]);
    a0.x += v0 * p00.x; a0.y += v0 * p00.y;
    a1.x += v0 * p01.x; a1.y += v0 * p01.y;
  }

  // Epilogue: bias + LN + GELU for both planes.
  float2 bv = *reinterpret_cast<const float2*>(&bias[2 * l]);
  float2 gv = *reinterpret_cast<const float2*>(&gamma[2 * l]);
  float2 ev = *reinterpret_cast<const float2*>(&beta[2 * l]);

  float h0x = a0.x + bv.x, h0y = a0.y + bv.y;
  float h1x = a1.x + bv.x, h1y = a1.y + bv.y;

  float s0 = h0x + h0y, q0 = h0x * h0x + h0y * h0y;
  float s1 = h1x + h1y, q1 = h1x * h1x + h1y * h1y;
#pragma unroll
  for (int off = 32; off >= 1; off >>= 1) {
    s0 += __shfl_xor(s0, off, 64);
    q0 += __shfl_xor(q0, off, 64);
    s1 += __shfl_xor(s1, off, 64);
    q1 += __shfl_xor(q1, off, 64);
  }
  float mu0 = s0 * (1.0f / 128.0f);
  float var0 = q0 * (1.0f / 128.0f) - mu0 * mu0;
  float inv0 = rsqrtf(var0 + LN_EPS);
  float mu1 = s1 * (1.0f / 128.0f);
  float var1 = q1 * (1.0f / 128.0f) - mu1 * mu1;
  float inv1 = rsqrtf(var1 + LN_EPS);

  float2 o0, o1;
  o0.x = gelu_exact((h0x - mu0) * inv0 * gv.x + ev.x);
  o0.y = gelu_exact((h0y - mu0) * inv0 * gv.y + ev.y);
  o1.x = gelu_exact((h1x - mu1) * inv1 * gv.x + ev.x);
  o1.y = gelu_exact((h1y - mu1) * inv1 * gv.y + ev.y);

  *reinterpret_cast<float2*>(&out[(size_t)r * D + 2 * l]) = o0;
  *reinterpret_cast<float2*>(&out[((size_t)N_NODES + r) * D + 2 * l]) = o1;
}

// ---------------------------------------------------------------------------
// kernel_launch
// ---------------------------------------------------------------------------
extern "C" void kernel_launch(void* const* d_in, const int* in_sizes, int n_in,
                              void* d_out, int out_size, void* d_ws, size_t ws_size,
                              hipStream_t stream) {
  const float* x      = (const float*)d_in[0];
  const int*   A_rows = (const int*)d_in[1];
  const int*   A_cols = (const int*)d_in[2];
  const float* A_vals = (const float*)d_in[3];
  const float* W      = (const float*)d_in[4];
  const float* b      = (const float*)d_in[5];
  const float* gamma  = (const float*)d_in[6];
  const float* beta   = (const float*)d_in[7];
  float* out = (float*)d_out;

  // Workspace layout (~57.9 MB)
  char* ws = (char*)d_ws;
  size_t off = 0;
  auto alloc = [&](size_t bytes) {
    char* p = ws + off;
    off += (bytes + 255) & ~(size_t)255;
    return p;
  };
  float*          zbuf  = (float*)alloc((size_t)M_ROWS * D * sizeof(float));  // 51.2 MB
  int*            offs  = (int*)alloc((size_t)N_NODES * sizeof(int));
  int*            bsum  = (int*)alloc(4096);
  int2*           epair = (int2*)alloc((size_t)N_EDGES * sizeof(int2));       // 6.4 MB
  unsigned short* wt_hi = (unsigned short*)alloc(128 * 128 * sizeof(unsigned short));
  unsigned short* wt_lo = (unsigned short*)alloc(128 * 128 * sizeof(unsigned short));

  const int nb = (N_NODES + 1023) / 1024;   // 49

  // W split (independent of everything else)
  k_splitw<<<64, 256, 0, stream>>>(W, wt_hi, wt_lo);

  // CSR build
  hipMemsetAsync(offs, 0, N_NODES * sizeof(int), stream);
  k_hist<<<(N_EDGES + 255) / 256, 256, 0, stream>>>(A_rows, offs);
  k_scan1<<<nb, 1024, 0, stream>>>(offs, bsum);
  k_scan2<<<1, 64, 0, stream>>>(bsum, nb);
  k_scan3<<<nb, 1024, 0, stream>>>(offs, bsum);
  k_scatter<<<(N_EDGES + 255) / 256, 256, 0, stream>>>(A_rows, A_cols, A_vals,
                                                       offs, epair);

  // z = x @ W  (split-bf16 MFMA)
  k_gemm_z<<<(N_TILES + 7) / 8, 512, 0, stream>>>(x, wt_hi, wt_lo, zbuf);

  // out = LN(GELU?) -- SpMM over z + bias + LN + GELU fused
  k_spmm_ln<<<N_NODES / 4, 256, 0, stream>>>(zbuf, offs, epair, b, gamma, beta, out);
}

// Round 6
// 279.428 us; speedup vs baseline: 1.6677x; 1.1989x over previous
//
#include <hip/hip_runtime.h>
#include <hip/hip_fp16.h>
#include <cstdint>
#include <cstddef>

#define N_NODES 50000
#define N_EDGES 800000
#define D 128
#define M_ROWS (2 * N_NODES)     // B*N rows
#define N_TILES (M_ROWS / 16)    // 6250 row-tiles for MFMA GEMM
#define LN_EPS 1e-5f

typedef __attribute__((ext_vector_type(8))) short bf16x8;
typedef __attribute__((ext_vector_type(4))) float f32x4;

__device__ inline unsigned short bf16_rne(float f) {
  unsigned u = __float_as_uint(f);
  unsigned r = (u + 0x7FFFu + ((u >> 16) & 1u)) >> 16;
  return (unsigned short)r;
}

// ---------------------------------------------------------------------------
// Fused prep: blocks 0..63 split W into transposed bf16 hi/lo planes,
// blocks 64.. histogram A_rows into offs (offs pre-zeroed by memset).
// ---------------------------------------------------------------------------
__global__ __launch_bounds__(256) void k_prep(const float* __restrict__ W,
                                              unsigned short* __restrict__ wt_hi,
                                              unsigned short* __restrict__ wt_lo,
                                              const int* __restrict__ rows,
                                              int* __restrict__ offs) {
  int b = blockIdx.x;
  if (b < 64) {
    int i = b * 256 + threadIdx.x;   // 16384 elements of W
    int d = i >> 7, j = i & 127;
    float v = W[i];
    unsigned short hb = bf16_rne(v);
    float rem = v - __uint_as_float((unsigned)hb << 16);
    wt_hi[j * 128 + d] = hb;
    wt_lo[j * 128 + d] = bf16_rne(rem);
  } else {
    int e = (b - 64) * 256 + threadIdx.x;
    if (e < N_EDGES) atomicAdd(&offs[rows[e]], 1);
  }
}

// ---------------------------------------------------------------------------
// 3-kernel exclusive scan (proven safe in round 2; no co-residency assumption)
// ---------------------------------------------------------------------------
__global__ __launch_bounds__(1024) void k_scan1(int* __restrict__ offs,
                                                int* __restrict__ bsum) {
  __shared__ int s[1024];
  int tid = threadIdx.x;
  int i = blockIdx.x * 1024 + tid;
  int v = (i < N_NODES) ? offs[i] : 0;
  s[tid] = v;
  __syncthreads();
  for (int o = 1; o < 1024; o <<= 1) {
    int t = (tid >= o) ? s[tid - o] : 0;
    __syncthreads();
    s[tid] += t;
    __syncthreads();
  }
  if (i < N_NODES) offs[i] = s[tid] - v;        // exclusive (block-local)
  if (tid == 1023) bsum[blockIdx.x] = s[tid];
}

__global__ void k_scan2(int* __restrict__ bsum, int nb) {
  if (threadIdx.x == 0) {
    int run = 0;
    for (int b = 0; b < nb; b++) { int t = bsum[b]; bsum[b] = run; run += t; }
  }
}

__global__ __launch_bounds__(1024) void k_scan3(int* __restrict__ offs,
                                                const int* __restrict__ bsum) {
  int i = blockIdx.x * 1024 + threadIdx.x;
  if (i < N_NODES) offs[i] += bsum[blockIdx.x];
}

// ---------------------------------------------------------------------------
// Scatter edges into CSR order; atomic cursor on offs itself (offs becomes
// per-row END offsets afterwards). epair = interleaved (col, val).
// ---------------------------------------------------------------------------
__global__ __launch_bounds__(256) void k_scatter(const int* __restrict__ rows,
                                                 const int* __restrict__ cols,
                                                 const float* __restrict__ vals,
                                                 int* __restrict__ offs,
                                                 int2* __restrict__ epair) {
  int e = blockIdx.x * 256 + threadIdx.x;
  if (e < N_EDGES) {
    int r = rows[e];
    int pos = atomicAdd(&offs[r], 1);
    int2 p; p.x = cols[e]; p.y = __float_as_int(vals[e]);
    epair[pos] = p;
  }
}

// ---------------------------------------------------------------------------
// z = x @ W via split-bf16 MFMA (3 terms), output fp16 [M_ROWS][128].
// W (hi+lo, transposed) staged in 64KB LDS with XOR-16B swizzle. After the
// MFMA loop the same LDS is reused (barrier-separated) to repack each wave's
// 16x128 fp16 tile so global stores are 256B-coalesced.
// ---------------------------------------------------------------------------
__global__ __launch_bounds__(512) void k_gemm_z(const float* __restrict__ x,
                                                const unsigned short* __restrict__ wt_hi,
                                                const unsigned short* __restrict__ wt_lo,
                                                __half* __restrict__ z) {
  __shared__ unsigned short lw[2][128 * 128];   // 64 KB
  int tid = threadIdx.x;

  // Stage W hi/lo into LDS (swizzled). 2048 16B-chunks per plane.
  for (int c = tid; c < 2048; c += 512) {
    int j = c >> 4;
    int k16 = c & 15;
    int soff = j * 256 + ((k16 * 16) ^ ((j & 7) << 4));
    *reinterpret_cast<float4*>(reinterpret_cast<char*>(lw[0]) + soff) =
        *reinterpret_cast<const float4*>(wt_hi + j * 128 + k16 * 8);
    *reinterpret_cast<float4*>(reinterpret_cast<char*>(lw[1]) + soff) =
        *reinterpret_cast<const float4*>(wt_lo + j * 128 + k16 * 8);
  }

  int wave = tid >> 6, l = tid & 63;
  int tile = blockIdx.x * 8 + wave;
  bool active = tile < N_TILES;
  int lrow = l & 15;
  int kg = l >> 4;                  // 0..3

  // x loads issued before the barrier so they overlap W staging.
  float4 xv[4][2];
  if (active) {
    const float* xr = x + (size_t)(tile * 16 + lrow) * D + kg * 8;
#pragma unroll
    for (int kc = 0; kc < 4; kc++) {
      xv[kc][0] = *reinterpret_cast<const float4*>(xr + kc * 32);
      xv[kc][1] = *reinterpret_cast<const float4*>(xr + kc * 32 + 4);
    }
  } else {
#pragma unroll
    for (int kc = 0; kc < 4; kc++) {
      xv[kc][0] = float4{0.f, 0.f, 0.f, 0.f};
      xv[kc][1] = float4{0.f, 0.f, 0.f, 0.f};
    }
  }
  __syncthreads();

  // Split A into hi/lo bf16 fragments.
  bf16x8 ahi[4], alo[4];
#pragma unroll
  for (int kc = 0; kc < 4; kc++) {
    float tmp[8];
    *reinterpret_cast<float4*>(&tmp[0]) = xv[kc][0];
    *reinterpret_cast<float4*>(&tmp[4]) = xv[kc][1];
    bf16x8 h, lo8;
#pragma unroll
    for (int e = 0; e < 8; e++) {
      unsigned short hb = bf16_rne(tmp[e]);
      float rem = tmp[e] - __uint_as_float((unsigned)hb << 16);
      h[e] = (short)hb;
      lo8[e] = (short)bf16_rne(rem);
    }
    ahi[kc] = h; alo[kc] = lo8;
  }

  f32x4 acc[8];
#pragma unroll
  for (int jt = 0; jt < 8; jt++) acc[jt] = (f32x4){0.f, 0.f, 0.f, 0.f};

#pragma unroll
  for (int kc = 0; kc < 4; kc++) {
#pragma unroll
    for (int jt = 0; jt < 8; jt++) {
      int j = jt * 16 + lrow;
      int kbyte = kc * 64 + kg * 16;
      int soff = j * 256 + (kbyte ^ ((j & 7) << 4));
      bf16x8 bhi = *reinterpret_cast<bf16x8*>(reinterpret_cast<char*>(lw[0]) + soff);
      bf16x8 blo = *reinterpret_cast<bf16x8*>(reinterpret_cast<char*>(lw[1]) + soff);
      acc[jt] = __builtin_amdgcn_mfma_f32_16x16x32_bf16(ahi[kc], bhi, acc[jt], 0, 0, 0);
      acc[jt] = __builtin_amdgcn_mfma_f32_16x16x32_bf16(alo[kc], bhi, acc[jt], 0, 0, 0);
      acc[jt] = __builtin_amdgcn_mfma_f32_16x16x32_bf16(ahi[kc], blo, acc[jt], 0, 0, 0);
    }
  }

  // All waves done reading W -> reuse LDS as per-wave repack buffers.
  __syncthreads();
  // Per-wave region: 16 rows x 136 halves (pad 8 to spread banks) = 4352 B.
  unsigned short* lds = &lw[0][0] + (size_t)wave * 2176;
  // C/D layout: col = lane&15, row = (lane>>4)*4 + reg.
  int rbase = kg * 4;
#pragma unroll
  for (int jt = 0; jt < 8; jt++) {
#pragma unroll
    for (int r = 0; r < 4; r++) {
      __half hv = __float2half(acc[jt][r]);
      lds[(rbase + r) * 136 + jt * 16 + lrow] = __half_as_ushort(hv);
    }
  }
  __syncthreads();   // explicit: repack writes visible before reads
  if (active) {
    const char* ldsb = reinterpret_cast<const char*>(lds);
#pragma unroll
    for (int r = 0; r < 16; r++) {
      unsigned v = *reinterpret_cast<const unsigned*>(ldsb + r * 272 + 4 * l);
      *reinterpret_cast<unsigned*>(&z[(size_t)(tile * 16 + r) * D + 2 * l]) = v;
    }
  }
}

// ---------------------------------------------------------------------------
// Pull SpMM over fp16 z, fused bias + LayerNorm + exact GELU. One wave per
// node row; lane l owns cols {2l, 2l+1} of both batch planes.
// offs[] holds END offsets post-scatter; start = offs[r-1].
// ---------------------------------------------------------------------------
__device__ inline float gelu_exact(float v) {
  return 0.5f * v * (1.0f + erff(v * 0.70710678118654752440f));
}

__global__ __launch_bounds__(256) void k_spmm_ln(const __half* __restrict__ z,
                                                 const int* __restrict__ offs,
                                                 const int2* __restrict__ epair,
                                                 const float* __restrict__ bias,
                                                 const float* __restrict__ gamma,
                                                 const float* __restrict__ beta,
                                                 float* __restrict__ out) {
  int r = blockIdx.x * 4 + (threadIdx.x >> 6);
  int l = threadIdx.x & 63;
  int start = (r == 0) ? 0 : offs[r - 1];
  int end = offs[r];

  float2 a0 = {0.f, 0.f}, a1 = {0.f, 0.f};
  const __half* z1 = z + (size_t)N_NODES * D;

  int k = start;
  for (; k + 1 < end; k += 2) {
    int2 e0 = epair[k];
    int2 e1 = epair[k + 1];
    size_t b0 = (size_t)e0.x * D + 2 * l;
    size_t b1 = (size_t)e1.x * D + 2 * l;
    float v0 = __int_as_float(e0.y);
    float v1 = __int_as_float(e1.y);
    float2 f00 = __half22float2(*reinterpret_cast<const __half2*>(&z[b0]));
    float2 f01 = __half22float2(*reinterpret_cast<const __half2*>(&z1[b0]));
    float2 f10 = __half22float2(*reinterpret_cast<const __half2*>(&z[b1]));
    float2 f11 = __half22float2(*reinterpret_cast<const __half2*>(&z1[b1]));
    a0.x += v0 * f00.x; a0.y += v0 * f00.y;
    a1.x += v0 * f01.x; a1.y += v0 * f01.y;
    a0.x += v1 * f10.x; a0.y += v1 * f10.y;
    a1.x += v1 * f11.x; a1.y += v1 * f11.y;
  }
  if (k < end) {
    int2 e0 = epair[k];
    size_t b0 = (size_t)e0.x * D + 2 * l;
    float v0 = __int_as_float(e0.y);
    float2 f00 = __half22float2(*reinterpret_cast<const __half2*>(&z[b0]));
    float2 f01 = __half22float2(*reinterpret_cast<const __half2*>(&z1[b0]));
    a0.x += v0 * f00.x; a0.y += v0 * f00.y;
    a1.x += v0 * f01.x; a1.y += v0 * f01.y;
  }

  // Epilogue: bias + LN + GELU for both planes.
  float2 bv = *reinterpret_cast<const float2*>(&bias[2 * l]);
  float2 gv = *reinterpret_cast<const float2*>(&gamma[2 * l]);
  float2 ev = *reinterpret_cast<const float2*>(&beta[2 * l]);

  float h0x = a0.x + bv.x, h0y = a0.y + bv.y;
  float h1x = a1.x + bv.x, h1y = a1.y + bv.y;

  float s0 = h0x + h0y, q0 = h0x * h0x + h0y * h0y;
  float s1 = h1x + h1y, q1 = h1x * h1x + h1y * h1y;
#pragma unroll
  for (int off = 32; off >= 1; off >>= 1) {
    s0 += __shfl_xor(s0, off, 64);
    q0 += __shfl_xor(q0, off, 64);
    s1 += __shfl_xor(s1, off, 64);
    q1 += __shfl_xor(q1, off, 64);
  }
  float mu0 = s0 * (1.0f / 128.0f);
  float var0 = q0 * (1.0f / 128.0f) - mu0 * mu0;
  float inv0 = rsqrtf(var0 + LN_EPS);
  float mu1 = s1 * (1.0f / 128.0f);
  float var1 = q1 * (1.0f / 128.0f) - mu1 * mu1;
  float inv1 = rsqrtf(var1 + LN_EPS);

  float2 o0, o1;
  o0.x = gelu_exact((h0x - mu0) * inv0 * gv.x + ev.x);
  o0.y = gelu_exact((h0y - mu0) * inv0 * gv.y + ev.y);
  o1.x = gelu_exact((h1x - mu1) * inv1 * gv.x + ev.x);
  o1.y = gelu_exact((h1y - mu1) * inv1 * gv.y + ev.y);

  *reinterpret_cast<float2*>(&out[(size_t)r * D + 2 * l]) = o0;
  *reinterpret_cast<float2*>(&out[((size_t)N_NODES + r) * D + 2 * l]) = o1;
}

// ---------------------------------------------------------------------------
// kernel_launch
// ---------------------------------------------------------------------------
extern "C" void kernel_launch(void* const* d_in, const int* in_sizes, int n_in,
                              void* d_out, int out_size, void* d_ws, size_t ws_size,
                              hipStream_t stream) {
  const float* x      = (const float*)d_in[0];
  const int*   A_rows = (const int*)d_in[1];
  const int*   A_cols = (const int*)d_in[2];
  const float* A_vals = (const float*)d_in[3];
  const float* W      = (const float*)d_in[4];
  const float* b      = (const float*)d_in[5];
  const float* gamma  = (const float*)d_in[6];
  const float* beta   = (const float*)d_in[7];
  float* out = (float*)d_out;

  // Workspace layout (~32.3 MB)
  char* ws = (char*)d_ws;
  size_t off = 0;
  auto alloc = [&](size_t bytes) {
    char* p = ws + off;
    off += (bytes + 255) & ~(size_t)255;
    return p;
  };
  __half*         zbuf  = (__half*)alloc((size_t)M_ROWS * D * sizeof(__half)); // 25.6 MB
  int*            offs  = (int*)alloc((size_t)N_NODES * sizeof(int));          // 200 KB
  int*            bsum  = (int*)alloc(4096);
  int2*           epair = (int2*)alloc((size_t)N_EDGES * sizeof(int2));        // 6.4 MB
  unsigned short* wt_hi = (unsigned short*)alloc(128 * 128 * sizeof(unsigned short));
  unsigned short* wt_lo = (unsigned short*)alloc(128 * 128 * sizeof(unsigned short));

  const int nb = (N_NODES + 1023) / 1024;   // 49

  hipMemsetAsync(offs, 0, N_NODES * sizeof(int), stream);

  // W split + edge histogram (fused)
  k_prep<<<64 + (N_EDGES + 255) / 256, 256, 0, stream>>>(W, wt_hi, wt_lo,
                                                         A_rows, offs);
  // Exclusive scan (3 kernels, no co-residency assumption)
  k_scan1<<<nb, 1024, 0, stream>>>(offs, bsum);
  k_scan2<<<1, 64, 0, stream>>>(bsum, nb);
  k_scan3<<<nb, 1024, 0, stream>>>(offs, bsum);
  // CSR scatter
  k_scatter<<<(N_EDGES + 255) / 256, 256, 0, stream>>>(A_rows, A_cols, A_vals,
                                                       offs, epair);
  // z = x @ W  (split-bf16 MFMA, fp16 output)
  k_gemm_z<<<(N_TILES + 7) / 8, 512, 0, stream>>>(x, wt_hi, wt_lo, zbuf);
  // SpMM over z + bias + LN + GELU fused
  k_spmm_ln<<<N_NODES / 4, 256, 0, stream>>>(zbuf, offs, epair, b, gamma, beta, out);
}

// Round 7
// 273.182 us; speedup vs baseline: 1.7058x; 1.0229x over previous
//
#include <hip/hip_runtime.h>
#include <hip/hip_fp16.h>
#include <cstdint>
#include <cstddef>

#define N_NODES 50000
#define N_EDGES 800000
#define D 128
#define M_ROWS (2 * N_NODES)      // B*N rows
#define N_TILES (M_ROWS / 16)     // 6250 row-tiles for MFMA GEMM
#define TILES_PER_BATCH (N_NODES / 16)   // 3125 (tiles never straddle batches)
#define GEMM_BLOCKS ((N_TILES + 7) / 8)  // 782
#define SCAT_BLOCKS ((N_EDGES + 511) / 512) // 1563
#define LN_EPS 1e-5f

typedef __attribute__((ext_vector_type(8))) short bf16x8;
typedef __attribute__((ext_vector_type(4))) float f32x4;

__device__ inline unsigned short bf16_rne(float f) {
  unsigned u = __float_as_uint(f);
  unsigned r = (u + 0x7FFFu + ((u >> 16) & 1u)) >> 16;
  return (unsigned short)r;
}

// ---------------------------------------------------------------------------
// Fused prep: blocks 0..63 split W into transposed bf16 hi/lo planes,
// blocks 64.. histogram A_rows into offs (4 edges/thread, int4 loads).
// ---------------------------------------------------------------------------
__global__ __launch_bounds__(256) void k_prep(const float* __restrict__ W,
                                              unsigned short* __restrict__ wt_hi,
                                              unsigned short* __restrict__ wt_lo,
                                              const int* __restrict__ rows,
                                              int* __restrict__ offs) {
  int b = blockIdx.x;
  if (b < 64) {
    int i = b * 256 + threadIdx.x;   // 16384 elements of W
    int d = i >> 7, j = i & 127;
    float v = W[i];
    unsigned short hb = bf16_rne(v);
    float rem = v - __uint_as_float((unsigned)hb << 16);
    wt_hi[j * 128 + d] = hb;
    wt_lo[j * 128 + d] = bf16_rne(rem);
  } else {
    int base = (b - 64) * 1024 + threadIdx.x * 4;
    if (base + 3 < N_EDGES) {
      int4 rr = *reinterpret_cast<const int4*>(&rows[base]);
      atomicAdd(&offs[rr.x], 1);
      atomicAdd(&offs[rr.y], 1);
      atomicAdd(&offs[rr.z], 1);
      atomicAdd(&offs[rr.w], 1);
    } else {
      for (int e = base; e < N_EDGES; e++) atomicAdd(&offs[rows[e]], 1);
    }
  }
}

// ---------------------------------------------------------------------------
// Exclusive scan, 2 kernels. scan1: per-block scan + block totals.
// scan3: each block wave-reduces its predecessor totals (<=48) itself.
// ---------------------------------------------------------------------------
__global__ __launch_bounds__(1024) void k_scan1(int* __restrict__ offs,
                                                int* __restrict__ bsum) {
  __shared__ int s[1024];
  int tid = threadIdx.x;
  int i = blockIdx.x * 1024 + tid;
  int v = (i < N_NODES) ? offs[i] : 0;
  s[tid] = v;
  __syncthreads();
  for (int o = 1; o < 1024; o <<= 1) {
    int t = (tid >= o) ? s[tid - o] : 0;
    __syncthreads();
    s[tid] += t;
    __syncthreads();
  }
  if (i < N_NODES) offs[i] = s[tid] - v;        // exclusive (block-local)
  if (tid == 1023) bsum[blockIdx.x] = s[tid];
}

__global__ __launch_bounds__(1024) void k_scan3(int* __restrict__ offs,
                                                const int* __restrict__ bsum) {
  __shared__ int spfx;
  int tid = threadIdx.x, bid = blockIdx.x;
  if (tid < 64) {
    int v = (tid < bid) ? bsum[tid] : 0;   // bid <= 48 < 64
#pragma unroll
    for (int o = 32; o >= 1; o >>= 1) v += __shfl_xor(v, o, 64);
    if (tid == 0) spfx = v;
  }
  __syncthreads();
  int i = bid * 1024 + tid;
  if (i < N_NODES) offs[i] += spfx;
}

// ---------------------------------------------------------------------------
// Fused: blocks [0, GEMM_BLOCKS) compute z = x @ W via split-bf16 MFMA
// (fp16 output, interleaved layout z[n][b*128 + d]); blocks [GEMM_BLOCKS, ..)
// scatter edges into CSR order (independent work, overlaps the GEMM).
// offs becomes per-row END offsets after the scatter.
// ---------------------------------------------------------------------------
__global__ __launch_bounds__(512) void k_gemm_scatter(
    const float* __restrict__ x,
    const unsigned short* __restrict__ wt_hi,
    const unsigned short* __restrict__ wt_lo,
    __half* __restrict__ z,
    const int* __restrict__ rows,
    const int* __restrict__ cols,
    const float* __restrict__ vals,
    int* __restrict__ offs,
    int2* __restrict__ epair) {
  __shared__ unsigned short lw[2][128 * 128];   // 64 KB
  if (blockIdx.x >= GEMM_BLOCKS) {
    // ---- scatter path (no barriers, whole block branches together) ----
    int e = (blockIdx.x - GEMM_BLOCKS) * 512 + threadIdx.x;
    if (e < N_EDGES) {
      int r = rows[e];
      int pos = atomicAdd(&offs[r], 1);
      int2 p; p.x = cols[e]; p.y = __float_as_int(vals[e]);
      epair[pos] = p;
    }
    return;
  }

  // ---- GEMM path ----
  int tid = threadIdx.x;
  // Stage W hi/lo into LDS (swizzled). 2048 16B-chunks per plane.
  for (int c = tid; c < 2048; c += 512) {
    int j = c >> 4;
    int k16 = c & 15;
    int soff = j * 256 + ((k16 * 16) ^ ((j & 7) << 4));
    *reinterpret_cast<float4*>(reinterpret_cast<char*>(lw[0]) + soff) =
        *reinterpret_cast<const float4*>(wt_hi + j * 128 + k16 * 8);
    *reinterpret_cast<float4*>(reinterpret_cast<char*>(lw[1]) + soff) =
        *reinterpret_cast<const float4*>(wt_lo + j * 128 + k16 * 8);
  }

  int wave = tid >> 6, l = tid & 63;
  int tile = blockIdx.x * 8 + wave;
  bool active = tile < N_TILES;
  int lrow = l & 15;
  int kg = l >> 4;                  // 0..3

  // x loads issued before the barrier so they overlap W staging.
  float4 xv[4][2];
  if (active) {
    const float* xr = x + (size_t)(tile * 16 + lrow) * D + kg * 8;
#pragma unroll
    for (int kc = 0; kc < 4; kc++) {
      xv[kc][0] = *reinterpret_cast<const float4*>(xr + kc * 32);
      xv[kc][1] = *reinterpret_cast<const float4*>(xr + kc * 32 + 4);
    }
  } else {
#pragma unroll
    for (int kc = 0; kc < 4; kc++) {
      xv[kc][0] = float4{0.f, 0.f, 0.f, 0.f};
      xv[kc][1] = float4{0.f, 0.f, 0.f, 0.f};
    }
  }
  __syncthreads();

  // Split A into hi/lo bf16 fragments.
  bf16x8 ahi[4], alo[4];
#pragma unroll
  for (int kc = 0; kc < 4; kc++) {
    float tmp[8];
    *reinterpret_cast<float4*>(&tmp[0]) = xv[kc][0];
    *reinterpret_cast<float4*>(&tmp[4]) = xv[kc][1];
    bf16x8 h, lo8;
#pragma unroll
    for (int e = 0; e < 8; e++) {
      unsigned short hb = bf16_rne(tmp[e]);
      float rem = tmp[e] - __uint_as_float((unsigned)hb << 16);
      h[e] = (short)hb;
      lo8[e] = (short)bf16_rne(rem);
    }
    ahi[kc] = h; alo[kc] = lo8;
  }

  f32x4 acc[8];
#pragma unroll
  for (int jt = 0; jt < 8; jt++) acc[jt] = (f32x4){0.f, 0.f, 0.f, 0.f};

#pragma unroll
  for (int kc = 0; kc < 4; kc++) {
#pragma unroll
    for (int jt = 0; jt < 8; jt++) {
      int j = jt * 16 + lrow;
      int kbyte = kc * 64 + kg * 16;
      int soff = j * 256 + (kbyte ^ ((j & 7) << 4));
      bf16x8 bhi = *reinterpret_cast<bf16x8*>(reinterpret_cast<char*>(lw[0]) + soff);
      bf16x8 blo = *reinterpret_cast<bf16x8*>(reinterpret_cast<char*>(lw[1]) + soff);
      acc[jt] = __builtin_amdgcn_mfma_f32_16x16x32_bf16(ahi[kc], bhi, acc[jt], 0, 0, 0);
      acc[jt] = __builtin_amdgcn_mfma_f32_16x16x32_bf16(alo[kc], bhi, acc[jt], 0, 0, 0);
      acc[jt] = __builtin_amdgcn_mfma_f32_16x16x32_bf16(ahi[kc], blo, acc[jt], 0, 0, 0);
    }
  }

  // Reuse LDS (barrier-separated) as per-wave fp16 repack buffers.
  __syncthreads();
  unsigned short* lds = &lw[0][0] + (size_t)wave * 2176;  // 16 x 136 halves
  int rbase = kg * 4;
#pragma unroll
  for (int jt = 0; jt < 8; jt++) {
#pragma unroll
    for (int r = 0; r < 4; r++) {
      __half hv = __float2half(acc[jt][r]);
      lds[(rbase + r) * 136 + jt * 16 + lrow] = __half_as_ushort(hv);
    }
  }
  __syncthreads();
  if (active) {
    int bb = (tile >= TILES_PER_BATCH);           // batch of this tile
    int n0 = tile * 16 - bb * N_NODES;            // node index of row 0
    const char* ldsb = reinterpret_cast<const char*>(lds);
    char* zb = reinterpret_cast<char*>(z);
#pragma unroll
    for (int r = 0; r < 16; r++) {
      unsigned v = *reinterpret_cast<const unsigned*>(ldsb + r * 272 + 4 * l);
      // interleaved: z[n][bb*128 + d]; 64 lanes x 4B = one 256B plane row
      *reinterpret_cast<unsigned*>(zb + (size_t)(n0 + r) * 512 + bb * 256 + 4 * l) = v;
    }
  }
}

// ---------------------------------------------------------------------------
// Pull SpMM over interleaved fp16 z + bias + LN + exact GELU. One wave per
// node; lane l owns cols 4*(l&31)..+3 of plane (l>>5). Each edge gather is
// one contiguous 512B wave read (uint2 per lane). Unroll-4 for MLP.
// ---------------------------------------------------------------------------
__device__ inline float gelu_exact(float v) {
  return 0.5f * v * (1.0f + erff(v * 0.70710678118654752440f));
}

__global__ __launch_bounds__(256) void k_spmm_ln(const __half* __restrict__ z,
                                                 const int* __restrict__ offs,
                                                 const int2* __restrict__ epair,
                                                 const float* __restrict__ bias,
                                                 const float* __restrict__ gamma,
                                                 const float* __restrict__ beta,
                                                 float* __restrict__ out) {
  int r = blockIdx.x * 4 + (threadIdx.x >> 6);
  int l = threadIdx.x & 63;
  int start = (r == 0) ? 0 : offs[r - 1];
  int end = offs[r];

  const char* zc = reinterpret_cast<const char*>(z);
  float4 acc = {0.f, 0.f, 0.f, 0.f};

  int k = start;
  for (; k + 3 < end; k += 4) {
    int2 e0 = epair[k];
    int2 e1 = epair[k + 1];
    int2 e2 = epair[k + 2];
    int2 e3 = epair[k + 3];
    uint2 p0 = *reinterpret_cast<const uint2*>(zc + (size_t)e0.x * 512 + 8 * l);
    uint2 p1 = *reinterpret_cast<const uint2*>(zc + (size_t)e1.x * 512 + 8 * l);
    uint2 p2 = *reinterpret_cast<const uint2*>(zc + (size_t)e2.x * 512 + 8 * l);
    uint2 p3 = *reinterpret_cast<const uint2*>(zc + (size_t)e3.x * 512 + 8 * l);
    float v0 = __int_as_float(e0.y), v1 = __int_as_float(e1.y);
    float v2 = __int_as_float(e2.y), v3 = __int_as_float(e3.y);
    {
      float2 lo = __half22float2(*reinterpret_cast<const __half2*>(&p0.x));
      float2 hi = __half22float2(*reinterpret_cast<const __half2*>(&p0.y));
      acc.x += v0 * lo.x; acc.y += v0 * lo.y; acc.z += v0 * hi.x; acc.w += v0 * hi.y;
    }
    {
      float2 lo = __half22float2(*reinterpret_cast<const __half2*>(&p1.x));
      float2 hi = __half22float2(*reinterpret_cast<const __half2*>(&p1.y));
      acc.x += v1 * lo.x; acc.y += v1 * lo.y; acc.z += v1 * hi.x; acc.w += v1 * hi.y;
    }
    {
      float2 lo = __half22float2(*reinterpret_cast<const __half2*>(&p2.x));
      float2 hi = __half22float2(*reinterpret_cast<const __half2*>(&p2.y));
      acc.x += v2 * lo.x; acc.y += v2 * lo.y; acc.z += v2 * hi.x; acc.w += v2 * hi.y;
    }
    {
      float2 lo = __half22float2(*reinterpret_cast<const __half2*>(&p3.x));
      float2 hi = __half22float2(*reinterpret_cast<const __half2*>(&p3.y));
      acc.x += v3 * lo.x; acc.y += v3 * lo.y; acc.z += v3 * hi.x; acc.w += v3 * hi.y;
    }
  }
  for (; k < end; k++) {
    int2 e0 = epair[k];
    uint2 p0 = *reinterpret_cast<const uint2*>(zc + (size_t)e0.x * 512 + 8 * l);
    float v0 = __int_as_float(e0.y);
    float2 lo = __half22float2(*reinterpret_cast<const __half2*>(&p0.x));
    float2 hi = __half22float2(*reinterpret_cast<const __half2*>(&p0.y));
    acc.x += v0 * lo.x; acc.y += v0 * lo.y; acc.z += v0 * hi.x; acc.w += v0 * hi.y;
  }

  // Epilogue: bias + LN + GELU. Plane p = l>>5; cols j0..j0+3, j0 = 4*(l&31).
  int p = l >> 5;
  int j0 = (l & 31) * 4;
  float4 bv = *reinterpret_cast<const float4*>(&bias[j0]);
  float4 gv = *reinterpret_cast<const float4*>(&gamma[j0]);
  float4 ev = *reinterpret_cast<const float4*>(&beta[j0]);

  float h0 = acc.x + bv.x, h1 = acc.y + bv.y, h2 = acc.z + bv.z, h3 = acc.w + bv.w;
  float s = h0 + h1 + h2 + h3;
  float q = h0 * h0 + h1 * h1 + h2 * h2 + h3 * h3;
  // reduce within each 32-lane half (xor of bits 0..4 stays in the half)
#pragma unroll
  for (int o = 16; o >= 1; o >>= 1) {
    s += __shfl_xor(s, o, 64);
    q += __shfl_xor(q, o, 64);
  }
  float mu = s * (1.0f / 128.0f);
  float var = q * (1.0f / 128.0f) - mu * mu;
  float inv = rsqrtf(var + LN_EPS);

  float4 o4;
  o4.x = gelu_exact((h0 - mu) * inv * gv.x + ev.x);
  o4.y = gelu_exact((h1 - mu) * inv * gv.y + ev.y);
  o4.z = gelu_exact((h2 - mu) * inv * gv.z + ev.z);
  o4.w = gelu_exact((h3 - mu) * inv * gv.w + ev.w);

  *reinterpret_cast<float4*>(&out[(size_t)p * N_NODES * D + (size_t)r * D + j0]) = o4;
}

// ---------------------------------------------------------------------------
// kernel_launch
// ---------------------------------------------------------------------------
extern "C" void kernel_launch(void* const* d_in, const int* in_sizes, int n_in,
                              void* d_out, int out_size, void* d_ws, size_t ws_size,
                              hipStream_t stream) {
  const float* x      = (const float*)d_in[0];
  const int*   A_rows = (const int*)d_in[1];
  const int*   A_cols = (const int*)d_in[2];
  const float* A_vals = (const float*)d_in[3];
  const float* W      = (const float*)d_in[4];
  const float* b      = (const float*)d_in[5];
  const float* gamma  = (const float*)d_in[6];
  const float* beta   = (const float*)d_in[7];
  float* out = (float*)d_out;

  // Workspace layout (~32.3 MB)
  char* ws = (char*)d_ws;
  size_t off = 0;
  auto alloc = [&](size_t bytes) {
    char* p = ws + off;
    off += (bytes + 255) & ~(size_t)255;
    return p;
  };
  __half*         zbuf  = (__half*)alloc((size_t)M_ROWS * D * sizeof(__half)); // 25.6 MB
  int*            offs  = (int*)alloc((size_t)N_NODES * sizeof(int));          // 200 KB
  int*            bsum  = (int*)alloc(4096);
  int2*           epair = (int2*)alloc((size_t)N_EDGES * sizeof(int2));        // 6.4 MB
  unsigned short* wt_hi = (unsigned short*)alloc(128 * 128 * sizeof(unsigned short));
  unsigned short* wt_lo = (unsigned short*)alloc(128 * 128 * sizeof(unsigned short));

  const int nb = (N_NODES + 1023) / 1024;   // 49

  hipMemsetAsync(offs, 0, N_NODES * sizeof(int), stream);

  // W split + edge histogram (fused, int4-batched)
  k_prep<<<64 + (N_EDGES / 4 + 255) / 256, 256, 0, stream>>>(W, wt_hi, wt_lo,
                                                             A_rows, offs);
  // Exclusive scan (2 kernels; scan3 self-computes block prefixes)
  k_scan1<<<nb, 1024, 0, stream>>>(offs, bsum);
  k_scan3<<<nb, 1024, 0, stream>>>(offs, bsum);
  // GEMM (z = x @ W, fp16 interleaved) + CSR scatter, fused/overlapped
  k_gemm_scatter<<<GEMM_BLOCKS + SCAT_BLOCKS, 512, 0, stream>>>(
      x, wt_hi, wt_lo, zbuf, A_rows, A_cols, A_vals, offs, epair);
  // SpMM over z + bias + LN + GELU fused
  k_spmm_ln<<<N_NODES / 4, 256, 0, stream>>>(zbuf, offs, epair, b, gamma, beta, out);
}